// Round 8
// baseline (584.116 us; speedup 1.0000x reference)
//
#include <hip/hip_runtime.h>
#include <math.h>

#define DIM 128
#define CAP 8192          // slots per bucket (mean fill 4096, sd ~64 -> never overflows)
#define BSHIFT 8          // 256 nodes per bucket
#define MAXNB 512         // max buckets supported (N <= 131072)

// ---------------------------------------------------------------- utilities
__global__ void k_zero_int(int* __restrict__ p, int n) {
    int i = blockIdx.x * blockDim.x + threadIdx.x;
    if (i < n) p[i] = 0;
}

// Pass A (block-batched): LDS histogram over buckets, ONE global reservation
// atomic per (block,bucket), then LDS-cursor writes into reserved runs.
__global__ __launch_bounds__(256) void k_bucket(const int* __restrict__ src,
                                                const int* __restrict__ dst,
                                                int* __restrict__ bcur,
                                                unsigned int* __restrict__ tmpe,
                                                int E, int NB, int chunk) {
    __shared__ int hist[MAXNB];
    __shared__ int cur[MAXNB];
    int t = threadIdx.x;
    int begE = blockIdx.x * chunk;
    int endE = begE + chunk;
    if (endE > E) endE = E;

    hist[t] = 0;
    hist[t + 256] = 0;
    __syncthreads();

    for (int e = begE + t; e < endE; e += 256) {
        atomicAdd(&hist[dst[e] >> BSHIFT], 1);
    }
    __syncthreads();

    if (t < NB)  cur[t]  = atomicAdd(&bcur[t], hist[t]);
    int t2 = t + 256;
    if (t2 < NB) cur[t2] = atomicAdd(&bcur[t2], hist[t2]);
    __syncthreads();

    for (int e = begE + t; e < endE; e += 256) {
        int s = src[e];
        int d = dst[e];
        int b = d >> BSHIFT;
        int p = atomicAdd(&cur[b], 1);   // LDS atomic
        if (p < CAP) tmpe[(size_t)b * CAP + p] = (unsigned int)s | ((unsigned int)(d & 255) << 17);
    }
}

// Pass B: one workgroup per bucket; LDS stage + histogram + scan + regroup.
__global__ __launch_bounds__(256) void k_scatter(unsigned int* __restrict__ tmpe,
                                                 const int* __restrict__ bcur,
                                                 int* __restrict__ rs,
                                                 int* __restrict__ cnt,
                                                 int N) {
    __shared__ unsigned int se[CAP];   // 32 KB
    __shared__ int hist[256];
    __shared__ int sh[256];
    __shared__ int cur[256];
    int b = blockIdx.x;
    int t = threadIdx.x;
    size_t base = (size_t)b * CAP;
    int m = bcur[b];
    if (m > CAP) m = CAP;
    for (int i = t; i < m; i += 256) se[i] = tmpe[base + i];
    hist[t] = 0;
    __syncthreads();
    for (int i = t; i < m; i += 256) atomicAdd(&hist[se[i] >> 17], 1);
    __syncthreads();
    int v = hist[t];
    sh[t] = v;
    __syncthreads();
    int run = v;
    for (int off = 1; off < 256; off <<= 1) {
        int y = (t >= off) ? sh[t - off] : 0;
        __syncthreads();
        run += y;
        sh[t] = run;
        __syncthreads();
    }
    int excl = run - v;
    int node = (b << BSHIFT) + t;
    if (node < N) {
        rs[node] = (int)base + excl;
        cnt[node] = v;
    }
    cur[t] = excl;
    __syncthreads();
    for (int i = t; i < m; i += 256) {
        unsigned int pk = se[i];
        int d = pk >> 17;
        int p = atomicAdd(&cur[d], 1);
        tmpe[base + p] = pk & 0x1FFFFu;
    }
}

// mean-aggregate: one wave per dst node; half-wave (32 lanes x float4) covers
// a full row; halves alternate edges; unroll-4 per half => 8 independent
// 512B row-gathers in flight per wave (latency fix: was 4).
__global__ __launch_bounds__(256) void k_agg(const float* __restrict__ in,
                                             const int* __restrict__ rs,
                                             const int* __restrict__ cnt,
                                             const unsigned int* __restrict__ esrc,
                                             float* __restrict__ msg, int N) {
    int w = threadIdx.x >> 6;            // wave within block
    int half = (threadIdx.x >> 5) & 1;   // half-wave id
    int l32 = threadIdx.x & 31;          // lane within half
    int node = blockIdx.x * 4 + w;
    if (node >= N) return;
    int beg = rs[node];
    int deg = cnt[node];
    int end = beg + deg;
    int c = l32 * 4;
    float ax = 0.f, ay = 0.f, az = 0.f, aw = 0.f;
    int e = beg + half;                  // this half's edges: stride 2
    for (; e + 6 < end; e += 8) {        // unroll 4: e, e+2, e+4, e+6
        int s0 = esrc[e];
        int s1 = esrc[e + 2];
        int s2 = esrc[e + 4];
        int s3 = esrc[e + 6];
        float4 u0 = *(const float4*)(in + (size_t)s0 * DIM + c);
        float4 u1 = *(const float4*)(in + (size_t)s1 * DIM + c);
        float4 u2 = *(const float4*)(in + (size_t)s2 * DIM + c);
        float4 u3 = *(const float4*)(in + (size_t)s3 * DIM + c);
        ax += (u0.x + u1.x) + (u2.x + u3.x);
        ay += (u0.y + u1.y) + (u2.y + u3.y);
        az += (u0.z + u1.z) + (u2.z + u3.z);
        aw += (u0.w + u1.w) + (u2.w + u3.w);
    }
    for (; e + 2 < end; e += 4) {        // tail unroll 2
        int s0 = esrc[e];
        int s1 = esrc[e + 2];
        float4 u0 = *(const float4*)(in + (size_t)s0 * DIM + c);
        float4 u1 = *(const float4*)(in + (size_t)s1 * DIM + c);
        ax += u0.x + u1.x;
        ay += u0.y + u1.y;
        az += u0.z + u1.z;
        aw += u0.w + u1.w;
    }
    if (e < end) {
        int s0 = esrc[e];
        float4 u0 = *(const float4*)(in + (size_t)s0 * DIM + c);
        ax += u0.x;
        ay += u0.y;
        az += u0.z;
        aw += u0.w;
    }
    ax += __shfl_xor(ax, 32);
    ay += __shfl_xor(ay, 32);
    az += __shfl_xor(az, 32);
    aw += __shfl_xor(aw, 32);
    if (half == 0) {
        float invd = 1.0f / fmaxf((float)deg, 1.0f);
        float4 o;
        o.x = ax * invd;
        o.y = ay * invd;
        o.z = az * invd;
        o.w = aw * invd;
        *(float4*)(msg + (size_t)node * DIM + c) = o;
    }
}

// fused dual GEMM: out[m] = A[m] @ Ws^T + Hn[m] @ Wn^T + bias
// 256 threads, tile 128 rows x 128 cols, 8x8 micro-tile/thread, K chunks of 32.
// Per kk: 4 ds_read_b128 -> 64 FMA (2x the FMA density of the 64-row version).
// Bs row stride 196 (=4 mod 32): grouped cols at 12*tc dwords -> 2-way bank
// aliasing only (free). Same K-summation order as before (bitwise-identical).
template <bool FUSE_NORM>
__global__ __launch_bounds__(256) void k_gemm(const float* __restrict__ A,
                                              const float* __restrict__ Hn,
                                              const float* __restrict__ Ws,
                                              const float* __restrict__ Wn,
                                              const float* __restrict__ bias,
                                              float* __restrict__ out, int N) {
    __shared__ float As[32][132];   // k-major; reads are 4-address broadcast
    __shared__ float Bs[32][196];   // k-major, grouped: col o at o + 4*(o>>3)
    int tid = threadIdx.x;
    int tr = tid >> 4;  // 0..15 -> row group (8 rows each)
    int tc = tid & 15;  // 0..15 -> col group (8 cols each)
    int m0 = blockIdx.x * 128;

    float acc[8][8];
#pragma unroll
    for (int i = 0; i < 8; ++i)
#pragma unroll
        for (int j = 0; j < 8; ++j) acc[i][j] = 0.f;

    for (int kb = 0; kb < 256; kb += 32) {
        const float* srcA = (kb < 128) ? A : Hn;
        const float* srcB = (kb < 128) ? Ws : Wn;
        int ka = kb & 127;
        // stage A tile: 128 rows x 32 k = 1024 float4, 4 per thread
#pragma unroll
        for (int i = 0; i < 4; ++i) {
            int fi = tid + i * 256;
            int row = fi >> 3, kq = fi & 7;
            int m = m0 + row;
            float4 v = make_float4(0.f, 0.f, 0.f, 0.f);
            if (m < N) v = *(const float4*)(srcA + (size_t)m * DIM + ka + kq * 4);
            As[kq * 4 + 0][row] = v.x;
            As[kq * 4 + 1][row] = v.y;
            As[kq * 4 + 2][row] = v.z;
            As[kq * 4 + 3][row] = v.w;
        }
        // stage B tile: 128 out x 32 k = 1024 float4, 4 per thread (grouped cols)
#pragma unroll
        for (int i = 0; i < 4; ++i) {
            int fi = tid + i * 256;
            int o = fi >> 3, kq = fi & 7;
            float4 v = *(const float4*)(srcB + o * DIM + ka + kq * 4);
            int oc = o + ((o >> 3) << 2);
            Bs[kq * 4 + 0][oc] = v.x;
            Bs[kq * 4 + 1][oc] = v.y;
            Bs[kq * 4 + 2][oc] = v.z;
            Bs[kq * 4 + 3][oc] = v.w;
        }
        __syncthreads();
#pragma unroll
        for (int kk = 0; kk < 32; ++kk) {
            float4 a0 = *(const float4*)&As[kk][tr * 8];
            float4 a1 = *(const float4*)&As[kk][tr * 8 + 4];
            int bc = tc * 12;   // = 8*tc + 4*tc (grouped physical col), 48B-aligned
            float4 b0 = *(const float4*)&Bs[kk][bc];
            float4 b1 = *(const float4*)&Bs[kk][bc + 4];
            float av[8] = {a0.x, a0.y, a0.z, a0.w, a1.x, a1.y, a1.z, a1.w};
            float bw[8] = {b0.x, b0.y, b0.z, b0.w, b1.x, b1.y, b1.z, b1.w};
#pragma unroll
            for (int i = 0; i < 8; ++i)
#pragma unroll
                for (int j = 0; j < 8; ++j) acc[i][j] += av[i] * bw[j];
        }
        __syncthreads();
    }
    float4 bb0 = *(const float4*)(bias + tc * 8);
    float4 bb1 = *(const float4*)(bias + tc * 8 + 4);
#pragma unroll
    for (int i = 0; i < 8; ++i) {
        int m = m0 + tr * 8 + i;
        if (m < N) {
            float4 o0, o1;
            o0.x = acc[i][0] + bb0.x;
            o0.y = acc[i][1] + bb0.y;
            o0.z = acc[i][2] + bb0.z;
            o0.w = acc[i][3] + bb0.w;
            o1.x = acc[i][4] + bb1.x;
            o1.y = acc[i][5] + bb1.y;
            o1.z = acc[i][6] + bb1.z;
            o1.w = acc[i][7] + bb1.w;
            if (FUSE_NORM) {
                // row m spans the 16 threads sharing tr (lanes tr*16..tr*16+15,
                // all within one wave): shfl_xor 8..1 reduces across the group.
                float ss = o0.x * o0.x + o0.y * o0.y + o0.z * o0.z + o0.w * o0.w
                         + o1.x * o1.x + o1.y * o1.y + o1.z * o1.z + o1.w * o1.w;
                ss += __shfl_xor(ss, 8);
                ss += __shfl_xor(ss, 4);
                ss += __shfl_xor(ss, 2);
                ss += __shfl_xor(ss, 1);
                float scale = 1.0f / fmaxf(sqrtf(ss), 1e-12f);
                o0.x *= scale; o0.y *= scale; o0.z *= scale; o0.w *= scale;
                o1.x *= scale; o1.y *= scale; o1.z *= scale; o1.w *= scale;
            }
            *(float4*)(out + (size_t)m * DIM + tc * 8) = o0;
            *(float4*)(out + (size_t)m * DIM + tc * 8 + 4) = o1;
        }
    }
}

extern "C" void kernel_launch(void* const* d_in, const int* in_sizes, int n_in,
                              void* d_out, int out_size, void* d_ws, size_t ws_size,
                              hipStream_t stream) {
    const float* x   = (const float*)d_in[0];
    const int*   src = (const int*)d_in[1];
    const int*   dst = (const int*)d_in[2];
    const float* Ws1 = (const float*)d_in[3];
    const float* Wn1 = (const float*)d_in[4];
    const float* b1  = (const float*)d_in[5];
    const float* Ws2 = (const float*)d_in[6];
    const float* Wn2 = (const float*)d_in[7];
    const float* b2  = (const float*)d_in[8];
    float* out = (float*)d_out;

    int N = in_sizes[0] / DIM;
    int E = in_sizes[1];
    int NB = (N + (1 << BSHIFT) - 1) >> BSHIFT;

    // workspace carve-up (256B aligned)
    char* p = (char*)d_ws;
    size_t off = 0;
    auto carve = [&](size_t bytes) {
        void* r = p + off;
        off = (off + bytes + 255) & ~(size_t)255;
        return r;
    };
    unsigned int* tmpe = (unsigned int*)carve((size_t)NB * CAP * 4);
    int* bcur = (int*)carve((size_t)NB * 4);
    int* rs   = (int*)carve((size_t)N * 4);
    int* cnt  = (int*)carve((size_t)N * 4);
    float* msg = (float*)carve((size_t)N * DIM * 4);
    float* h1  = (float*)carve((size_t)N * DIM * 4);

    // ---- CSR build (bucketed two-pass, block-batched reservations) ----
    int grid_b = 256;
    int chunk = (E + grid_b - 1) / grid_b;
    k_zero_int<<<(NB + 255) / 256, 256, 0, stream>>>(bcur, NB);
    k_bucket<<<grid_b, 256, 0, stream>>>(src, dst, bcur, tmpe, E, NB, chunk);
    k_scatter<<<NB, 256, 0, stream>>>(tmpe, bcur, rs, cnt, N);

    // ---- layer 1 ----
    k_agg<<<(N + 3) / 4, 256, 0, stream>>>(x, rs, cnt, tmpe, msg, N);
    k_gemm<false><<<(N + 127) / 128, 256, 0, stream>>>(x, msg, Ws1, Wn1, b1, h1, N);

    // ---- layer 2 (norm fused into epilogue) ----
    k_agg<<<(N + 3) / 4, 256, 0, stream>>>(h1, rs, cnt, tmpe, msg, N);
    k_gemm<true><<<(N + 127) / 128, 256, 0, stream>>>(h1, msg, Ws2, Wn2, b2, out, N);
}

// Round 9
// 457.437 us; speedup vs baseline: 1.2769x; 1.2769x over previous
//
#include <hip/hip_runtime.h>
#include <math.h>

#define DIM 128
#define CAP 8192          // slots per bucket (mean fill 4096, sd ~64 -> never overflows)
#define BSHIFT 8          // 256 nodes per bucket
#define MAXNB 512         // max buckets supported (N <= 131072)

typedef __attribute__((ext_vector_type(8))) short bf16x8;
typedef __attribute__((ext_vector_type(8))) unsigned short us8;
typedef __attribute__((ext_vector_type(4))) float f32x4;

__device__ __forceinline__ unsigned short f2bf_rne(float f) {
    unsigned int u = __float_as_uint(f);
    unsigned int r = (u + 0x7FFFu + ((u >> 16) & 1u)) >> 16;
    return (unsigned short)r;
}
__device__ __forceinline__ float bf2f(unsigned short h) {
    return __uint_as_float(((unsigned int)h) << 16);
}

// ---------------------------------------------------------------- utilities
__global__ void k_zero_int(int* __restrict__ p, int n) {
    int i = blockIdx.x * blockDim.x + threadIdx.x;
    if (i < n) p[i] = 0;
}

// one-time weight conversion: Wcat[layer][n][k] (k<128 self, k>=128 neigh)
// -> bf16 hi and lo planes, [2][128][256] each.
__global__ __launch_bounds__(256) void k_wcvt(const float* __restrict__ Ws1,
                                              const float* __restrict__ Wn1,
                                              const float* __restrict__ Ws2,
                                              const float* __restrict__ Wn2,
                                              unsigned short* __restrict__ Wh,
                                              unsigned short* __restrict__ Wl) {
    int i = blockIdx.x * 256 + threadIdx.x;   // 0 .. 65535
    int l = i >> 15;
    int rem = i & 32767;
    int n = rem >> 8;
    int k = rem & 255;
    const float* W = (k < 128) ? (l ? Ws2 : Ws1) : (l ? Wn2 : Wn1);
    float f = W[n * 128 + (k & 127)];
    unsigned short h = f2bf_rne(f);
    Wh[i] = h;
    Wl[i] = f2bf_rne(f - bf2f(h));
}

// Pass A (block-batched): LDS histogram over buckets, ONE global reservation
// atomic per (block,bucket), then LDS-cursor writes into reserved runs.
__global__ __launch_bounds__(256) void k_bucket(const int* __restrict__ src,
                                                const int* __restrict__ dst,
                                                int* __restrict__ bcur,
                                                unsigned int* __restrict__ tmpe,
                                                int E, int NB, int chunk) {
    __shared__ int hist[MAXNB];
    __shared__ int cur[MAXNB];
    int t = threadIdx.x;
    int begE = blockIdx.x * chunk;
    int endE = begE + chunk;
    if (endE > E) endE = E;

    hist[t] = 0;
    hist[t + 256] = 0;
    __syncthreads();

    for (int e = begE + t; e < endE; e += 256) {
        atomicAdd(&hist[dst[e] >> BSHIFT], 1);
    }
    __syncthreads();

    if (t < NB)  cur[t]  = atomicAdd(&bcur[t], hist[t]);
    int t2 = t + 256;
    if (t2 < NB) cur[t2] = atomicAdd(&bcur[t2], hist[t2]);
    __syncthreads();

    for (int e = begE + t; e < endE; e += 256) {
        int s = src[e];
        int d = dst[e];
        int b = d >> BSHIFT;
        int p = atomicAdd(&cur[b], 1);   // LDS atomic
        if (p < CAP) tmpe[(size_t)b * CAP + p] = (unsigned int)s | ((unsigned int)(d & 255) << 17);
    }
}

// Pass B: one workgroup per bucket; LDS stage + histogram + scan + regroup.
__global__ __launch_bounds__(256) void k_scatter(unsigned int* __restrict__ tmpe,
                                                 const int* __restrict__ bcur,
                                                 int* __restrict__ rs,
                                                 int* __restrict__ cnt,
                                                 int N) {
    __shared__ unsigned int se[CAP];   // 32 KB
    __shared__ int hist[256];
    __shared__ int sh[256];
    __shared__ int cur[256];
    int b = blockIdx.x;
    int t = threadIdx.x;
    size_t base = (size_t)b * CAP;
    int m = bcur[b];
    if (m > CAP) m = CAP;
    for (int i = t; i < m; i += 256) se[i] = tmpe[base + i];
    hist[t] = 0;
    __syncthreads();
    for (int i = t; i < m; i += 256) atomicAdd(&hist[se[i] >> 17], 1);
    __syncthreads();
    int v = hist[t];
    sh[t] = v;
    __syncthreads();
    int run = v;
    for (int off = 1; off < 256; off <<= 1) {
        int y = (t >= off) ? sh[t - off] : 0;
        __syncthreads();
        run += y;
        sh[t] = run;
        __syncthreads();
    }
    int excl = run - v;
    int node = (b << BSHIFT) + t;
    if (node < N) {
        rs[node] = (int)base + excl;
        cnt[node] = v;
    }
    cur[t] = excl;
    __syncthreads();
    for (int i = t; i < m; i += 256) {
        unsigned int pk = se[i];
        int d = pk >> 17;
        int p = atomicAdd(&cur[d], 1);
        tmpe[base + p] = pk & 0x1FFFFu;
    }
}

// mean-aggregate: one wave per dst node; half-wave (32 lanes x float4) covers
// a full row; halves alternate edges; unroll-4 per half => 8 independent
// 512B row-gathers in flight per wave.
__global__ __launch_bounds__(256) void k_agg(const float* __restrict__ in,
                                             const int* __restrict__ rs,
                                             const int* __restrict__ cnt,
                                             const unsigned int* __restrict__ esrc,
                                             float* __restrict__ msg, int N) {
    int w = threadIdx.x >> 6;            // wave within block
    int half = (threadIdx.x >> 5) & 1;   // half-wave id
    int l32 = threadIdx.x & 31;          // lane within half
    int node = blockIdx.x * 4 + w;
    if (node >= N) return;
    int beg = rs[node];
    int deg = cnt[node];
    int end = beg + deg;
    int c = l32 * 4;
    float ax = 0.f, ay = 0.f, az = 0.f, aw = 0.f;
    int e = beg + half;                  // this half's edges: stride 2
    for (; e + 6 < end; e += 8) {        // unroll 4
        int s0 = esrc[e];
        int s1 = esrc[e + 2];
        int s2 = esrc[e + 4];
        int s3 = esrc[e + 6];
        float4 u0 = *(const float4*)(in + (size_t)s0 * DIM + c);
        float4 u1 = *(const float4*)(in + (size_t)s1 * DIM + c);
        float4 u2 = *(const float4*)(in + (size_t)s2 * DIM + c);
        float4 u3 = *(const float4*)(in + (size_t)s3 * DIM + c);
        ax += (u0.x + u1.x) + (u2.x + u3.x);
        ay += (u0.y + u1.y) + (u2.y + u3.y);
        az += (u0.z + u1.z) + (u2.z + u3.z);
        aw += (u0.w + u1.w) + (u2.w + u3.w);
    }
    for (; e + 2 < end; e += 4) {        // tail unroll 2
        int s0 = esrc[e];
        int s1 = esrc[e + 2];
        float4 u0 = *(const float4*)(in + (size_t)s0 * DIM + c);
        float4 u1 = *(const float4*)(in + (size_t)s1 * DIM + c);
        ax += u0.x + u1.x;
        ay += u0.y + u1.y;
        az += u0.z + u1.z;
        aw += u0.w + u1.w;
    }
    if (e < end) {
        int s0 = esrc[e];
        float4 u0 = *(const float4*)(in + (size_t)s0 * DIM + c);
        ax += u0.x;
        ay += u0.y;
        az += u0.z;
        aw += u0.w;
    }
    ax += __shfl_xor(ax, 32);
    ay += __shfl_xor(ay, 32);
    az += __shfl_xor(az, 32);
    aw += __shfl_xor(aw, 32);
    if (half == 0) {
        float invd = 1.0f / fmaxf((float)deg, 1.0f);
        float4 o;
        o.x = ax * invd;
        o.y = ay * invd;
        o.z = az * invd;
        o.w = aw * invd;
        *(float4*)(msg + (size_t)node * DIM + c) = o;
    }
}

// split-bf16 MFMA dual GEMM: out[m] = A[m]@Ws^T + Hn[m]@Wn^T + bias.
// Block 128 rows x 128 cols, 4 waves x 32 rows (2 row-tiles of 16).
// K concat = 256, chunks of 64, mfma_f32_16x16x32_bf16, 3-term hi/lo split
// (ah*bh + ah*bl + al*bh; al*bl ~2^-16 dropped).
// LDS tiles XOR-swizzled on 16B granules (k8 ^= row&7): <=2 lanes/bank.
// Fragment layouts (verified, m89/m91): A/B lane holds row/col=lane&15,
// k=(lane>>4)*8+e ; C/D col=lane&15, row=(lane>>4)*4+reg.
template <bool FUSE_NORM>
__global__ __launch_bounds__(256) void k_gemm(const float* __restrict__ A,
                                              const float* __restrict__ Hn,
                                              const unsigned short* __restrict__ Wh,
                                              const unsigned short* __restrict__ Wl,
                                              const float* __restrict__ bias,
                                              float* __restrict__ out, int N, int layer) {
    __shared__ __align__(16) unsigned short Ah[128 * 64];
    __shared__ __align__(16) unsigned short Al[128 * 64];
    __shared__ __align__(16) unsigned short Bh[128 * 64];
    __shared__ __align__(16) unsigned short Bl[128 * 64];
    int tid = threadIdx.x;
    int w = tid >> 6;
    int lane = tid & 63;
    int l4 = lane & 15;
    int g = lane >> 4;
    int m0 = blockIdx.x * 128;
    const unsigned short* WhL = Wh + layer * 128 * 256;
    const unsigned short* WlL = Wl + layer * 128 * 256;

    f32x4 acc[2][8];
#pragma unroll
    for (int rt = 0; rt < 2; ++rt)
#pragma unroll
        for (int ct = 0; ct < 8; ++ct) acc[rt][ct] = (f32x4){0.f, 0.f, 0.f, 0.f};

    for (int kb = 0; kb < 256; kb += 64) {
        const float* srcA = (kb < 128) ? A : Hn;
        int ka = kb & 127;
        // stage A chunk: 128 rows x 64 k, fp32 -> bf16 hi/lo, swizzled
#pragma unroll
        for (int i = 0; i < 4; ++i) {
            int seg = tid + i * 256;          // 1024 segs of 8 k
            int row = seg >> 3, k8 = seg & 7;
            int m = m0 + row;
            float4 v0 = make_float4(0.f, 0.f, 0.f, 0.f);
            float4 v1 = make_float4(0.f, 0.f, 0.f, 0.f);
            if (m < N) {
                const float* p = srcA + (size_t)m * DIM + ka + k8 * 8;
                v0 = *(const float4*)p;
                v1 = *(const float4*)(p + 4);
            }
            float f[8] = {v0.x, v0.y, v0.z, v0.w, v1.x, v1.y, v1.z, v1.w};
            us8 hv, lv;
#pragma unroll
            for (int j = 0; j < 8; ++j) {
                unsigned short h = f2bf_rne(f[j]);
                hv[j] = h;
                lv[j] = f2bf_rne(f[j] - bf2f(h));
            }
            int us = row * 64 + ((k8 ^ (row & 7)) << 3);
            *(us8*)&Ah[us] = hv;
            *(us8*)&Al[us] = lv;
        }
        // stage B chunk: 128 n x 64 k from pre-converted bf16 planes, swizzled
#pragma unroll
        for (int i = 0; i < 4; ++i) {
            int seg = tid + i * 256;
            int n = seg >> 3, k8 = seg & 7;
            int gi = n * 256 + kb + k8 * 8;
            us8 hv = *(const us8*)&WhL[gi];
            us8 lv = *(const us8*)&WlL[gi];
            int us = n * 64 + ((k8 ^ (n & 7)) << 3);
            *(us8*)&Bh[us] = hv;
            *(us8*)&Bl[us] = lv;
        }
        __syncthreads();
#pragma unroll
        for (int ks = 0; ks < 2; ++ks) {
            bf16x8 ah[2], al[2];
#pragma unroll
            for (int rt = 0; rt < 2; ++rt) {
                int row = w * 32 + rt * 16 + l4;
                int us = row * 64 + (((ks * 4 + g) ^ (row & 7)) << 3);
                ah[rt] = *(const bf16x8*)&Ah[us];
                al[rt] = *(const bf16x8*)&Al[us];
            }
#pragma unroll
            for (int ct = 0; ct < 8; ++ct) {
                int n = ct * 16 + l4;
                int us = n * 64 + (((ks * 4 + g) ^ (n & 7)) << 3);
                bf16x8 bh = *(const bf16x8*)&Bh[us];
                bf16x8 bl = *(const bf16x8*)&Bl[us];
#pragma unroll
                for (int rt = 0; rt < 2; ++rt) {
                    acc[rt][ct] = __builtin_amdgcn_mfma_f32_16x16x32_bf16(ah[rt], bh, acc[rt][ct], 0, 0, 0);
                    acc[rt][ct] = __builtin_amdgcn_mfma_f32_16x16x32_bf16(ah[rt], bl, acc[rt][ct], 0, 0, 0);
                    acc[rt][ct] = __builtin_amdgcn_mfma_f32_16x16x32_bf16(al[rt], bh, acc[rt][ct], 0, 0, 0);
                }
            }
        }
        __syncthreads();
    }

    float bv[8];
#pragma unroll
    for (int ct = 0; ct < 8; ++ct) bv[ct] = bias[ct * 16 + l4];
#pragma unroll
    for (int rt = 0; rt < 2; ++rt) {
        int rbase = m0 + w * 32 + rt * 16 + g * 4;
        float vals[8][4];
#pragma unroll
        for (int ct = 0; ct < 8; ++ct)
#pragma unroll
            for (int r = 0; r < 4; ++r) vals[ct][r] = acc[rt][ct][r] + bv[ct];
        if (FUSE_NORM) {
            float ss[4];
#pragma unroll
            for (int r = 0; r < 4; ++r) {
                float s = 0.f;
#pragma unroll
                for (int ct = 0; ct < 8; ++ct) s += vals[ct][r] * vals[ct][r];
                // reduce across the 16 lanes sharing group g (cols 0..127)
                s += __shfl_xor(s, 1);
                s += __shfl_xor(s, 2);
                s += __shfl_xor(s, 4);
                s += __shfl_xor(s, 8);
                ss[r] = s;
            }
#pragma unroll
            for (int r = 0; r < 4; ++r) {
                float sc = 1.0f / fmaxf(sqrtf(ss[r]), 1e-12f);
#pragma unroll
                for (int ct = 0; ct < 8; ++ct) vals[ct][r] *= sc;
            }
        }
#pragma unroll
        for (int r = 0; r < 4; ++r) {
            int m = rbase + r;
            if (m < N) {
#pragma unroll
                for (int ct = 0; ct < 8; ++ct)
                    out[(size_t)m * DIM + ct * 16 + l4] = vals[ct][r];
            }
        }
    }
}

extern "C" void kernel_launch(void* const* d_in, const int* in_sizes, int n_in,
                              void* d_out, int out_size, void* d_ws, size_t ws_size,
                              hipStream_t stream) {
    const float* x   = (const float*)d_in[0];
    const int*   src = (const int*)d_in[1];
    const int*   dst = (const int*)d_in[2];
    const float* Ws1 = (const float*)d_in[3];
    const float* Wn1 = (const float*)d_in[4];
    const float* b1  = (const float*)d_in[5];
    const float* Ws2 = (const float*)d_in[6];
    const float* Wn2 = (const float*)d_in[7];
    const float* b2  = (const float*)d_in[8];
    float* out = (float*)d_out;

    int N = in_sizes[0] / DIM;
    int E = in_sizes[1];
    int NB = (N + (1 << BSHIFT) - 1) >> BSHIFT;

    // workspace carve-up (256B aligned)
    char* p = (char*)d_ws;
    size_t off = 0;
    auto carve = [&](size_t bytes) {
        void* r = p + off;
        off = (off + bytes + 255) & ~(size_t)255;
        return r;
    };
    unsigned int* tmpe = (unsigned int*)carve((size_t)NB * CAP * 4);
    int* bcur = (int*)carve((size_t)NB * 4);
    int* rs   = (int*)carve((size_t)N * 4);
    int* cnt  = (int*)carve((size_t)N * 4);
    float* msg = (float*)carve((size_t)N * DIM * 4);
    float* h1  = (float*)carve((size_t)N * DIM * 4);
    unsigned short* Wh = (unsigned short*)carve((size_t)2 * 128 * 256 * 2);
    unsigned short* Wl = (unsigned short*)carve((size_t)2 * 128 * 256 * 2);

    // ---- weight bf16 hi/lo pre-conversion (once) ----
    k_wcvt<<<256, 256, 0, stream>>>(Ws1, Wn1, Ws2, Wn2, Wh, Wl);

    // ---- CSR build (bucketed two-pass, block-batched reservations) ----
    int grid_b = 256;
    int chunk = (E + grid_b - 1) / grid_b;
    k_zero_int<<<(NB + 255) / 256, 256, 0, stream>>>(bcur, NB);
    k_bucket<<<grid_b, 256, 0, stream>>>(src, dst, bcur, tmpe, E, NB, chunk);
    k_scatter<<<NB, 256, 0, stream>>>(tmpe, bcur, rs, cnt, N);

    // ---- layer 1 ----
    k_agg<<<(N + 3) / 4, 256, 0, stream>>>(x, rs, cnt, tmpe, msg, N);
    k_gemm<false><<<(N + 127) / 128, 256, 0, stream>>>(x, msg, Wh, Wl, b1, h1, N, 0);

    // ---- layer 2 (norm fused into epilogue) ----
    k_agg<<<(N + 3) / 4, 256, 0, stream>>>(h1, rs, cnt, tmpe, msg, N);
    k_gemm<true><<<(N + 127) / 128, 256, 0, stream>>>(h1, msg, Wh, Wl, b2, out, N, 1);
}

// Round 10
// 384.415 us; speedup vs baseline: 1.5195x; 1.1900x over previous
//
#include <hip/hip_runtime.h>
#include <math.h>

#define DIM 128
#define CAP 8192          // slots per bucket (mean fill 4096, sd ~64 -> never overflows)
#define BSHIFT 8          // 256 nodes per bucket
#define MAXNB 512         // max buckets supported (N <= 131072)

typedef __attribute__((ext_vector_type(8))) short bf16x8;
typedef __attribute__((ext_vector_type(8))) unsigned short us8;
typedef __attribute__((ext_vector_type(4))) float f32x4;

__device__ __forceinline__ unsigned short f2bf_rne(float f) {
    unsigned int u = __float_as_uint(f);
    unsigned int r = (u + 0x7FFFu + ((u >> 16) & 1u)) >> 16;
    return (unsigned short)r;
}
__device__ __forceinline__ float bf2f(unsigned short h) {
    return __uint_as_float(((unsigned int)h) << 16);
}

// ---------------------------------------------------------------- utilities
__global__ void k_zero_int(int* __restrict__ p, int n) {
    int i = blockIdx.x * blockDim.x + threadIdx.x;
    if (i < n) p[i] = 0;
}

// fp32 -> bf16 copy (for the aggregation gather operand), float4-vectorized
__global__ __launch_bounds__(256) void k_xcvt(const float* __restrict__ in,
                                              unsigned short* __restrict__ outb,
                                              int n4) {
    int i = blockIdx.x * 256 + threadIdx.x;
    int stride = gridDim.x * 256;
    for (; i < n4; i += stride) {
        float4 v = *(const float4*)(in + (size_t)i * 4);
        ushort4 o;
        o.x = f2bf_rne(v.x);
        o.y = f2bf_rne(v.y);
        o.z = f2bf_rne(v.z);
        o.w = f2bf_rne(v.w);
        *(ushort4*)(outb + (size_t)i * 4) = o;
    }
}

// one-time weight conversion: Wcat[layer][n][k] (k<128 self, k>=128 neigh)
// -> bf16 hi and lo planes, [2][128][256] each.
__global__ __launch_bounds__(256) void k_wcvt(const float* __restrict__ Ws1,
                                              const float* __restrict__ Wn1,
                                              const float* __restrict__ Ws2,
                                              const float* __restrict__ Wn2,
                                              unsigned short* __restrict__ Wh,
                                              unsigned short* __restrict__ Wl) {
    int i = blockIdx.x * 256 + threadIdx.x;   // 0 .. 65535
    int l = i >> 15;
    int rem = i & 32767;
    int n = rem >> 8;
    int k = rem & 255;
    const float* W = (k < 128) ? (l ? Ws2 : Ws1) : (l ? Wn2 : Wn1);
    float f = W[n * 128 + (k & 127)];
    unsigned short h = f2bf_rne(f);
    Wh[i] = h;
    Wl[i] = f2bf_rne(f - bf2f(h));
}

// Pass A (block-batched): LDS histogram over buckets, ONE global reservation
// atomic per (block,bucket), then LDS-cursor writes into reserved runs.
__global__ __launch_bounds__(256) void k_bucket(const int* __restrict__ src,
                                                const int* __restrict__ dst,
                                                int* __restrict__ bcur,
                                                unsigned int* __restrict__ tmpe,
                                                int E, int NB, int chunk) {
    __shared__ int hist[MAXNB];
    __shared__ int cur[MAXNB];
    int t = threadIdx.x;
    int begE = blockIdx.x * chunk;
    int endE = begE + chunk;
    if (endE > E) endE = E;

    hist[t] = 0;
    hist[t + 256] = 0;
    __syncthreads();

    for (int e = begE + t; e < endE; e += 256) {
        atomicAdd(&hist[dst[e] >> BSHIFT], 1);
    }
    __syncthreads();

    if (t < NB)  cur[t]  = atomicAdd(&bcur[t], hist[t]);
    int t2 = t + 256;
    if (t2 < NB) cur[t2] = atomicAdd(&bcur[t2], hist[t2]);
    __syncthreads();

    for (int e = begE + t; e < endE; e += 256) {
        int s = src[e];
        int d = dst[e];
        int b = d >> BSHIFT;
        int p = atomicAdd(&cur[b], 1);   // LDS atomic
        if (p < CAP) tmpe[(size_t)b * CAP + p] = (unsigned int)s | ((unsigned int)(d & 255) << 17);
    }
}

// Pass B: one workgroup per bucket; LDS stage + histogram + scan + regroup.
__global__ __launch_bounds__(256) void k_scatter(unsigned int* __restrict__ tmpe,
                                                 const int* __restrict__ bcur,
                                                 int* __restrict__ rs,
                                                 int* __restrict__ cnt,
                                                 int N) {
    __shared__ unsigned int se[CAP];   // 32 KB
    __shared__ int hist[256];
    __shared__ int sh[256];
    __shared__ int cur[256];
    int b = blockIdx.x;
    int t = threadIdx.x;
    size_t base = (size_t)b * CAP;
    int m = bcur[b];
    if (m > CAP) m = CAP;
    for (int i = t; i < m; i += 256) se[i] = tmpe[base + i];
    hist[t] = 0;
    __syncthreads();
    for (int i = t; i < m; i += 256) atomicAdd(&hist[se[i] >> 17], 1);
    __syncthreads();
    int v = hist[t];
    sh[t] = v;
    __syncthreads();
    int run = v;
    for (int off = 1; off < 256; off <<= 1) {
        int y = (t >= off) ? sh[t - off] : 0;
        __syncthreads();
        run += y;
        sh[t] = run;
        __syncthreads();
    }
    int excl = run - v;
    int node = (b << BSHIFT) + t;
    if (node < N) {
        rs[node] = (int)base + excl;
        cnt[node] = v;
    }
    cur[t] = excl;
    __syncthreads();
    for (int i = t; i < m; i += 256) {
        unsigned int pk = se[i];
        int d = pk >> 17;
        int p = atomicAdd(&cur[d], 1);
        tmpe[base + p] = pk & 0x1FFFFu;
    }
}

// mean-aggregate from BF16 rows: one wave per dst node; half-wave (32 lanes
// x ushort4 = 256B) covers a full row; halves alternate edges; unroll-4 per
// half => 8 independent 256B row-gathers in flight. fp32 accumulate, fp32 out.
__global__ __launch_bounds__(256) void k_agg(const unsigned short* __restrict__ in,
                                             const int* __restrict__ rs,
                                             const int* __restrict__ cnt,
                                             const unsigned int* __restrict__ esrc,
                                             float* __restrict__ msg, int N) {
    int w = threadIdx.x >> 6;            // wave within block
    int half = (threadIdx.x >> 5) & 1;   // half-wave id
    int l32 = threadIdx.x & 31;          // lane within half
    int node = blockIdx.x * 4 + w;
    if (node >= N) return;
    int beg = rs[node];
    int deg = cnt[node];
    int end = beg + deg;
    int c = l32 * 4;                     // 4 bf16 columns per lane
    float ax = 0.f, ay = 0.f, az = 0.f, aw = 0.f;
    int e = beg + half;                  // this half's edges: stride 2
    for (; e + 6 < end; e += 8) {        // unroll 4
        int s0 = esrc[e];
        int s1 = esrc[e + 2];
        int s2 = esrc[e + 4];
        int s3 = esrc[e + 6];
        ushort4 u0 = *(const ushort4*)(in + (size_t)s0 * DIM + c);
        ushort4 u1 = *(const ushort4*)(in + (size_t)s1 * DIM + c);
        ushort4 u2 = *(const ushort4*)(in + (size_t)s2 * DIM + c);
        ushort4 u3 = *(const ushort4*)(in + (size_t)s3 * DIM + c);
        ax += (bf2f(u0.x) + bf2f(u1.x)) + (bf2f(u2.x) + bf2f(u3.x));
        ay += (bf2f(u0.y) + bf2f(u1.y)) + (bf2f(u2.y) + bf2f(u3.y));
        az += (bf2f(u0.z) + bf2f(u1.z)) + (bf2f(u2.z) + bf2f(u3.z));
        aw += (bf2f(u0.w) + bf2f(u1.w)) + (bf2f(u2.w) + bf2f(u3.w));
    }
    for (; e + 2 < end; e += 4) {        // tail unroll 2
        int s0 = esrc[e];
        int s1 = esrc[e + 2];
        ushort4 u0 = *(const ushort4*)(in + (size_t)s0 * DIM + c);
        ushort4 u1 = *(const ushort4*)(in + (size_t)s1 * DIM + c);
        ax += bf2f(u0.x) + bf2f(u1.x);
        ay += bf2f(u0.y) + bf2f(u1.y);
        az += bf2f(u0.z) + bf2f(u1.z);
        aw += bf2f(u0.w) + bf2f(u1.w);
    }
    if (e < end) {
        int s0 = esrc[e];
        ushort4 u0 = *(const ushort4*)(in + (size_t)s0 * DIM + c);
        ax += bf2f(u0.x);
        ay += bf2f(u0.y);
        az += bf2f(u0.z);
        aw += bf2f(u0.w);
    }
    ax += __shfl_xor(ax, 32);
    ay += __shfl_xor(ay, 32);
    az += __shfl_xor(az, 32);
    aw += __shfl_xor(aw, 32);
    if (half == 0) {
        float invd = 1.0f / fmaxf((float)deg, 1.0f);
        float4 o;
        o.x = ax * invd;
        o.y = ay * invd;
        o.z = az * invd;
        o.w = aw * invd;
        *(float4*)(msg + (size_t)node * DIM + c) = o;
    }
}

// split-bf16 MFMA dual GEMM: out[m] = A[m]@Ws^T + Hn[m]@Wn^T + bias.
// Block 128 rows x 128 cols, 4 waves x 32 rows (2 row-tiles of 16).
// K concat = 256, chunks of 64, mfma_f32_16x16x32_bf16, 3-term hi/lo split.
// When !FUSE_NORM (layer 1): also emit a bf16 copy (outb) for layer-2 agg.
template <bool FUSE_NORM>
__global__ __launch_bounds__(256) void k_gemm(const float* __restrict__ A,
                                              const float* __restrict__ Hn,
                                              const unsigned short* __restrict__ Wh,
                                              const unsigned short* __restrict__ Wl,
                                              const float* __restrict__ bias,
                                              float* __restrict__ out,
                                              unsigned short* __restrict__ outb,
                                              int N, int layer) {
    __shared__ __align__(16) unsigned short Ah[128 * 64];
    __shared__ __align__(16) unsigned short Al[128 * 64];
    __shared__ __align__(16) unsigned short Bh[128 * 64];
    __shared__ __align__(16) unsigned short Bl[128 * 64];
    int tid = threadIdx.x;
    int w = tid >> 6;
    int lane = tid & 63;
    int l4 = lane & 15;
    int g = lane >> 4;
    int m0 = blockIdx.x * 128;
    const unsigned short* WhL = Wh + layer * 128 * 256;
    const unsigned short* WlL = Wl + layer * 128 * 256;

    f32x4 acc[2][8];
#pragma unroll
    for (int rt = 0; rt < 2; ++rt)
#pragma unroll
        for (int ct = 0; ct < 8; ++ct) acc[rt][ct] = (f32x4){0.f, 0.f, 0.f, 0.f};

    for (int kb = 0; kb < 256; kb += 64) {
        const float* srcA = (kb < 128) ? A : Hn;
        int ka = kb & 127;
        // stage A chunk: 128 rows x 64 k, fp32 -> bf16 hi/lo, swizzled
#pragma unroll
        for (int i = 0; i < 4; ++i) {
            int seg = tid + i * 256;          // 1024 segs of 8 k
            int row = seg >> 3, k8 = seg & 7;
            int m = m0 + row;
            float4 v0 = make_float4(0.f, 0.f, 0.f, 0.f);
            float4 v1 = make_float4(0.f, 0.f, 0.f, 0.f);
            if (m < N) {
                const float* p = srcA + (size_t)m * DIM + ka + k8 * 8;
                v0 = *(const float4*)p;
                v1 = *(const float4*)(p + 4);
            }
            float f[8] = {v0.x, v0.y, v0.z, v0.w, v1.x, v1.y, v1.z, v1.w};
            us8 hv, lv;
#pragma unroll
            for (int j = 0; j < 8; ++j) {
                unsigned short h = f2bf_rne(f[j]);
                hv[j] = h;
                lv[j] = f2bf_rne(f[j] - bf2f(h));
            }
            int us = row * 64 + ((k8 ^ (row & 7)) << 3);
            *(us8*)&Ah[us] = hv;
            *(us8*)&Al[us] = lv;
        }
        // stage B chunk: 128 n x 64 k from pre-converted bf16 planes, swizzled
#pragma unroll
        for (int i = 0; i < 4; ++i) {
            int seg = tid + i * 256;
            int n = seg >> 3, k8 = seg & 7;
            int gi = n * 256 + kb + k8 * 8;
            us8 hv = *(const us8*)&WhL[gi];
            us8 lv = *(const us8*)&WlL[gi];
            int us = n * 64 + ((k8 ^ (n & 7)) << 3);
            *(us8*)&Bh[us] = hv;
            *(us8*)&Bl[us] = lv;
        }
        __syncthreads();
#pragma unroll
        for (int ks = 0; ks < 2; ++ks) {
            bf16x8 ah[2], al[2];
#pragma unroll
            for (int rt = 0; rt < 2; ++rt) {
                int row = w * 32 + rt * 16 + l4;
                int us = row * 64 + (((ks * 4 + g) ^ (row & 7)) << 3);
                ah[rt] = *(const bf16x8*)&Ah[us];
                al[rt] = *(const bf16x8*)&Al[us];
            }
#pragma unroll
            for (int ct = 0; ct < 8; ++ct) {
                int n = ct * 16 + l4;
                int us = n * 64 + (((ks * 4 + g) ^ (n & 7)) << 3);
                bf16x8 bh = *(const bf16x8*)&Bh[us];
                bf16x8 bl = *(const bf16x8*)&Bl[us];
#pragma unroll
                for (int rt = 0; rt < 2; ++rt) {
                    acc[rt][ct] = __builtin_amdgcn_mfma_f32_16x16x32_bf16(ah[rt], bh, acc[rt][ct], 0, 0, 0);
                    acc[rt][ct] = __builtin_amdgcn_mfma_f32_16x16x32_bf16(ah[rt], bl, acc[rt][ct], 0, 0, 0);
                    acc[rt][ct] = __builtin_amdgcn_mfma_f32_16x16x32_bf16(al[rt], bh, acc[rt][ct], 0, 0, 0);
                }
            }
        }
        __syncthreads();
    }

    float bv[8];
#pragma unroll
    for (int ct = 0; ct < 8; ++ct) bv[ct] = bias[ct * 16 + l4];
#pragma unroll
    for (int rt = 0; rt < 2; ++rt) {
        int rbase = m0 + w * 32 + rt * 16 + g * 4;
        float vals[8][4];
#pragma unroll
        for (int ct = 0; ct < 8; ++ct)
#pragma unroll
            for (int r = 0; r < 4; ++r) vals[ct][r] = acc[rt][ct][r] + bv[ct];
        if (FUSE_NORM) {
            float ss[4];
#pragma unroll
            for (int r = 0; r < 4; ++r) {
                float s = 0.f;
#pragma unroll
                for (int ct = 0; ct < 8; ++ct) s += vals[ct][r] * vals[ct][r];
                s += __shfl_xor(s, 1);
                s += __shfl_xor(s, 2);
                s += __shfl_xor(s, 4);
                s += __shfl_xor(s, 8);
                ss[r] = s;
            }
#pragma unroll
            for (int r = 0; r < 4; ++r) {
                float sc = 1.0f / fmaxf(sqrtf(ss[r]), 1e-12f);
#pragma unroll
                for (int ct = 0; ct < 8; ++ct) vals[ct][r] *= sc;
            }
        }
#pragma unroll
        for (int r = 0; r < 4; ++r) {
            int m = rbase + r;
            if (m < N) {
#pragma unroll
                for (int ct = 0; ct < 8; ++ct) {
                    out[(size_t)m * DIM + ct * 16 + l4] = vals[ct][r];
                    if (!FUSE_NORM)
                        outb[(size_t)m * DIM + ct * 16 + l4] = f2bf_rne(vals[ct][r]);
                }
            }
        }
    }
}

extern "C" void kernel_launch(void* const* d_in, const int* in_sizes, int n_in,
                              void* d_out, int out_size, void* d_ws, size_t ws_size,
                              hipStream_t stream) {
    const float* x   = (const float*)d_in[0];
    const int*   src = (const int*)d_in[1];
    const int*   dst = (const int*)d_in[2];
    const float* Ws1 = (const float*)d_in[3];
    const float* Wn1 = (const float*)d_in[4];
    const float* b1  = (const float*)d_in[5];
    const float* Ws2 = (const float*)d_in[6];
    const float* Wn2 = (const float*)d_in[7];
    const float* b2  = (const float*)d_in[8];
    float* out = (float*)d_out;

    int N = in_sizes[0] / DIM;
    int E = in_sizes[1];
    int NB = (N + (1 << BSHIFT) - 1) >> BSHIFT;

    // workspace carve-up (256B aligned)
    char* p = (char*)d_ws;
    size_t off = 0;
    auto carve = [&](size_t bytes) {
        void* r = p + off;
        off = (off + bytes + 255) & ~(size_t)255;
        return r;
    };
    unsigned int* tmpe = (unsigned int*)carve((size_t)NB * CAP * 4);
    int* bcur = (int*)carve((size_t)NB * 4);
    int* rs   = (int*)carve((size_t)N * 4);
    int* cnt  = (int*)carve((size_t)N * 4);
    float* msg = (float*)carve((size_t)N * DIM * 4);
    float* h1  = (float*)carve((size_t)N * DIM * 4);
    unsigned short* xb  = (unsigned short*)carve((size_t)N * DIM * 2);
    unsigned short* h1b = (unsigned short*)carve((size_t)N * DIM * 2);
    unsigned short* Wh = (unsigned short*)carve((size_t)2 * 128 * 256 * 2);
    unsigned short* Wl = (unsigned short*)carve((size_t)2 * 128 * 256 * 2);

    // ---- one-time conversions ----
    k_wcvt<<<256, 256, 0, stream>>>(Ws1, Wn1, Ws2, Wn2, Wh, Wl);
    k_xcvt<<<2048, 256, 0, stream>>>(x, xb, N * DIM / 4);

    // ---- CSR build (bucketed two-pass, block-batched reservations) ----
    int grid_b = 256;
    int chunk = (E + grid_b - 1) / grid_b;
    k_zero_int<<<(NB + 255) / 256, 256, 0, stream>>>(bcur, NB);
    k_bucket<<<grid_b, 256, 0, stream>>>(src, dst, bcur, tmpe, E, NB, chunk);
    k_scatter<<<NB, 256, 0, stream>>>(tmpe, bcur, rs, cnt, N);

    // ---- layer 1 ----
    k_agg<<<(N + 3) / 4, 256, 0, stream>>>(xb, rs, cnt, tmpe, msg, N);
    k_gemm<false><<<(N + 127) / 128, 256, 0, stream>>>(x, msg, Wh, Wl, b1, h1, h1b, N, 0);

    // ---- layer 2 (norm fused into epilogue) ----
    k_agg<<<(N + 3) / 4, 256, 0, stream>>>(h1b, rs, cnt, tmpe, msg, N);
    k_gemm<true><<<(N + 127) / 128, 256, 0, stream>>>(h1, msg, Wh, Wl, b2, out, nullptr, N, 1);
}